// Round 12
// baseline (969.014 us; speedup 1.0000x reference)
//
#include <hip/hip_runtime.h>
#include <hip/hip_bf16.h>
#include <math.h>

#define N_NODES 50000
#define N_EDGES 800000
#define N_GRAPHS 256
#define DIM 64
#define EDIM 50
#define HDIM 128
#define NLAYER 4
#define ZDIM (2 * DIM + EDIM)  // 178
#define NTILES (N_EDGES / 32)  // 25000

typedef __attribute__((ext_vector_type(8))) short short8v;
typedef __attribute__((ext_vector_type(16))) float f32x16;

__device__ __forceinline__ float softplus_f(float x) {
    return fmaxf(x, 0.0f) + log1pf(__expf(-fabsf(x)));
}

// branchless sigmoid: t=2^(-x/ln2); large -x -> t=inf -> rcp(inf)=0 (correct tail)
__device__ __forceinline__ float sigx(float x) {
    float t = __builtin_amdgcn_exp2f(-1.44269504f * x);
    return __builtin_amdgcn_rcpf(1.0f + t);
}
// STABLE softplus in exp2 domain: exact in the linear tail (no clamp truncation)
__device__ __forceinline__ float spx(float y) {
    float t = __builtin_amdgcn_exp2f(-1.44269504f * fabsf(y));
    return fmaxf(y, 0.0f) + 0.69314718f * __builtin_amdgcn_logf(1.0f + t);
}

__device__ __forceinline__ short cvt_bf16(float f) {
    __hip_bfloat16 h = __float2bfloat16(f);
    return *reinterpret_cast<short*>(&h);
}

// Weight tiles, column layout colv = g*64 + d (g: 0=sigmoid/Wf, 1=softplus/Ws)
// wcat[l][k][colv] = (k<50) ? W_g[l][128+k][d] : 0   (k padded to 64)
__global__ void k_wcat(const float* __restrict__ Wf, const float* __restrict__ Ws,
                       short* __restrict__ wcat) {
    int i = blockIdx.x * 256 + threadIdx.x;  // 4*64*128 = 32768
    int l = i >> 13;
    int rem = i & 8191;
    int k = rem >> 7;
    int colv = rem & 127;
    int g = colv >> 6, d = colv & 63;
    float v = 0.0f;
    if (k < 50) {
        const float* W = g ? Ws : Wf;
        v = W[((size_t)l * ZDIM + 128 + k) * 64 + d];
    }
    wcat[i] = cvt_bf16(v);
}

// ---------------- dst-sort (counting sort) ----------------
__global__ void k_hist(const int* __restrict__ eidx, int* __restrict__ hist) {
    int e = blockIdx.x * 256 + threadIdx.x;  // E exact
    atomicAdd(&hist[eidx[N_EDGES + e]], 1);
}

__global__ __launch_bounds__(256) void k_scan1(const int* __restrict__ hist,
                                               int* __restrict__ scanbuf,
                                               int* __restrict__ blocksums) {
    int tid = threadIdx.x;
    int i = blockIdx.x * 256 + tid;
    int v = (i < N_NODES) ? hist[i] : 0;
    int lane = tid & 63;
#pragma unroll
    for (int off = 1; off < 64; off <<= 1) {
        int u = __shfl_up(v, off);
        if (lane >= off) v += u;
    }
    __shared__ int wsum[4];
    if (lane == 63) wsum[tid >> 6] = v;
    __syncthreads();
    int w = tid >> 6;
    int add = 0;
#pragma unroll
    for (int k = 0; k < 3; ++k)
        if (k < w) add += wsum[k];
    v += add;
    if (i < N_NODES) scanbuf[i] = v;
    if (tid == 255) blocksums[blockIdx.x] = v;
}

__global__ __launch_bounds__(256) void k_scan2(int* __restrict__ blocksums, int nb) {
    int tid = threadIdx.x;
    int v = (tid < nb) ? blocksums[tid] : 0;
    int lane = tid & 63;
#pragma unroll
    for (int off = 1; off < 64; off <<= 1) {
        int u = __shfl_up(v, off);
        if (lane >= off) v += u;
    }
    __shared__ int wsum[4];
    if (lane == 63) wsum[tid >> 6] = v;
    __syncthreads();
    int w = tid >> 6;
    int add = 0;
#pragma unroll
    for (int k = 0; k < 3; ++k)
        if (k < w) add += wsum[k];
    v += add;
    if (tid < nb) blocksums[tid] = v;
}

__global__ void k_scan3(const int* __restrict__ scanbuf, const int* __restrict__ hist,
                        const int* __restrict__ blocksums, int* __restrict__ cursor) {
    int i = blockIdx.x * 256 + threadIdx.x;
    if (i >= N_NODES) return;
    int b = blockIdx.x;
    int off = b ? blocksums[b - 1] : 0;
    cursor[i] = scanbuf[i] - hist[i] + off;
}

__global__ void k_scatter(const int* __restrict__ eidx, int* __restrict__ cursor,
                          int* __restrict__ perm, int* __restrict__ permSrc,
                          int* __restrict__ permDst) {
    int e = blockIdx.x * 256 + threadIdx.x;
    int d = eidx[N_EDGES + e];
    int pos = atomicAdd(&cursor[d], 1);
    perm[pos] = e;
    permDst[pos] = d;
    permSrc[pos] = eidx[e];
}

// Sorted pack: thread = (tile, lane); handles all 4 kk fragments.
__global__ __launch_bounds__(256) void k_eprep2(const float* __restrict__ eattr,
                                                const int* __restrict__ perm,
                                                short* __restrict__ eattrP) {
    int i = blockIdx.x * 256 + threadIdx.x;  // over NTILES*64 = 1.6M
    int lane = i & 63;
    int tile = i >> 6;
    int pos = tile * 32 + (lane & 31);
    int h2 = lane >> 5;
    int edge = perm[pos];
    const float* erow = eattr + (size_t)edge * EDIM;  // 8B-aligned (200*edge)
    int k0 = 8 * h2;
    float2 v[12];
#pragma unroll
    for (int kk = 0; kk < 3; ++kk) {
#pragma unroll
        for (int p = 0; p < 4; ++p) {
            v[kk * 4 + p] = *(const float2*)(erow + k0 + 16 * kk + 2 * p);
        }
    }
    float2 t48 = make_float2(0.0f, 0.0f);
    if (h2 == 0) t48 = *(const float2*)(erow + 48);

    size_t fb = ((size_t)tile * 4) * 64 + lane;
#pragma unroll
    for (int kk = 0; kk < 3; ++kk) {
        short8v o;
#pragma unroll
        for (int p = 0; p < 4; ++p) {
            o[2 * p] = cvt_bf16(v[kk * 4 + p].x);
            o[2 * p + 1] = cvt_bf16(v[kk * 4 + p].y);
        }
        *(short8v*)&eattrP[(fb + (size_t)kk * 64) * 8] = o;
    }
    short8v o;
#pragma unroll
    for (int e = 0; e < 8; ++e) o[e] = 0;
    o[0] = cvt_bf16(t48.x);
    o[1] = cvt_bf16(t48.y);
    *(short8v*)&eattrP[(fb + 3 * 64) * 8] = o;
}

// Node-side matmuls, output layout [n][colv], colv = g*64+d.
// MODE 0: read h.  MODE 1: v=softplus(h+agg), write h, zero agg (fused update).
// MODE 2: v=emb[x[n]], write h (fused embed).
template <int MODE>
__global__ __launch_bounds__(256) void k_nodemm(
    const float* __restrict__ hin, float* __restrict__ hout, float* __restrict__ agg,
    const int* __restrict__ x, const float* __restrict__ emb,
    const float* __restrict__ Wf, const float* __restrict__ bf,
    const float* __restrict__ Ws, const float* __restrict__ bs,
    float* __restrict__ dstpack, float* __restrict__ srcpack) {
    __shared__ float hs[64 * 68];
    int tid = threadIdx.x;
    int w = tid >> 6, lane = tid & 63;
    int n0 = blockIdx.x * 64;
    for (int idx = tid; idx < 64 * 64; idx += 256) {
        int i = idx >> 6, k = idx & 63;
        int n = n0 + i;
        float v = 0.0f;
        if (n < N_NODES) {
            if (MODE == 0) {
                v = hin[(size_t)n * DIM + k];
            } else if (MODE == 1) {
                v = softplus_f(hin[(size_t)n * DIM + k] + agg[(size_t)n * DIM + k]);
                agg[(size_t)n * DIM + k] = 0.0f;
                hout[(size_t)n * DIM + k] = v;
            } else {
                v = emb[x[n] * DIM + k];
                hout[(size_t)n * DIM + k] = v;
            }
        }
        hs[i * 68 + k] = v;
    }
    __syncthreads();
    const float* Wsel = (w & 1) ? Ws : Wf;
    int row0 = (w < 2) ? 0 : 64;
    float wcol[64];
#pragma unroll
    for (int k = 0; k < 64; ++k) wcol[k] = Wsel[(row0 + k) * 64 + lane];
    float bias = (w == 0) ? bf[lane] : (w == 1) ? bs[lane] : 0.0f;
    float* outp = (w < 2) ? dstpack : srcpack;
    int colv = (w & 1) * 64 + lane;
    int nmax = min(64, N_NODES - n0);
    for (int i = 0; i < nmax; ++i) {
        float acc = bias;
#pragma unroll
        for (int k = 0; k < 64; k += 4) {
            float4 hv = *(const float4*)&hs[i * 68 + k];
            acc += hv.x * wcol[k] + hv.y * wcol[k + 1] + hv.z * wcol[k + 2] + hv.w * wcol[k + 3];
        }
        outp[(size_t)(n0 + i) * 128 + colv] = acc;
    }
}

// ---------------- sorted edge kernel: ONE WAVE PER TILE ----------------
// Each wave computes all 4 feature slices of its 32-edge tile:
//   slice s (sig, d in [32s,32s+32)) pairs with slice s+2 (softplus, same d)
//   in the SAME lane, same register index -> gate pairing fully in-register.
// LDS (per wave, private) only for the edge-axis segmented scan.
__global__ __launch_bounds__(256) void k_edge_s(
    const int* __restrict__ permSrc, const int* __restrict__ permDst,
    const short* __restrict__ eattrP, const float* __restrict__ dstpack,
    const float* __restrict__ srcpack, const short* __restrict__ wcat_l,
    float* __restrict__ agg) {
    __shared__ float msgS[4][32][68];  // [wave][edge][d], pitch 68 (16B-aligned rows)
    __shared__ int dshS[4][32];
    int tid = threadIdx.x;
    int w = tid >> 6;
    int lane = tid & 63;
    int c = lane & 31;   // edge within tile
    int h2 = lane >> 5;

    float* msgW = &msgS[w][0][0];
    int* dshW = dshS[w];

    // Weight A-fragments for ALL 4 slices: wfr[s][kk]
    short8v wfr[4][4];
#pragma unroll
    for (int s = 0; s < 4; ++s) {
#pragma unroll
        for (int kk = 0; kk < 4; ++kk) {
#pragma unroll
            for (int e = 0; e < 8; ++e) {
                wfr[s][kk][e] = wcat_l[(kk * 16 + 8 * h2 + e) * 128 + s * 32 + c];
            }
        }
    }

    for (int tile = blockIdx.x * 4 + w; tile < NTILES; tile += gridDim.x * 4) {
        int e0 = tile * 32;
        int tI = permDst[e0 + c];
        int sI = permSrc[e0 + c];
        if (lane < 32) dshW[lane] = tI;

        short8v efr[4];
#pragma unroll
        for (int kk = 0; kk < 4; ++kk) {
            efr[kk] = *(const short8v*)&eattrP[(((size_t)tile * 4 + kk) * 64 + lane) * 8];
        }

        const float* drow = dstpack + (((size_t)(unsigned)tI) << 7);
        const float* srow = srcpack + (((size_t)(unsigned)sI) << 7);

        // slice pairs (0,2) then (1,3): d = 32*sp2 + 8*q + 4*h2 + i
#pragma unroll
        for (int sp2 = 0; sp2 < 2; ++sp2) {
            f32x16 aS, aP;
#pragma unroll
            for (int i = 0; i < 16; ++i) { aS[i] = 0.0f; aP[i] = 0.0f; }
#pragma unroll
            for (int kk = 0; kk < 4; ++kk) {
                aS = __builtin_amdgcn_mfma_f32_32x32x16_bf16(wfr[sp2][kk], efr[kk], aS, 0, 0, 0);
            }
#pragma unroll
            for (int kk = 0; kk < 4; ++kk) {
                aP = __builtin_amdgcn_mfma_f32_32x32x16_bf16(wfr[sp2 + 2][kk], efr[kk], aP, 0, 0, 0);
            }
#pragma unroll
            for (int q = 0; q < 4; ++q) {
                int d0 = 32 * sp2 + 8 * q + 4 * h2;
                float4 dvS = *(const float4*)(drow + d0);
                float4 svS = *(const float4*)(srow + d0);
                float4 dvP = *(const float4*)(drow + 64 + d0);
                float4 svP = *(const float4*)(srow + 64 + d0);
                float4 mo;
#pragma unroll
                for (int i = 0; i < 4; ++i) {
                    float ps = aS[4 * q + i] + dvS[i] + svS[i];
                    float pp = aP[4 * q + i] + dvP[i] + svP[i];
                    mo[i] = sigx(ps) * spx(pp);
                }
                *(float4*)&msgW[c * 68 + d0] = mo;  // 272B row pitch: 16B-aligned
            }
        }

        __builtin_amdgcn_wave_barrier();

        // segmented scan over edges, lane owns d = lane (0..63).
        // dshW[e] is wave-uniform -> boundary branch is s_cbranch-skipped;
        // flush atomics are coalesced 256B bursts.
        {
            float accum = 0.0f;
            int cur = dshW[0];
            const float* mcol = msgW + lane;
#pragma unroll
            for (int e = 0; e < 32; ++e) {
                int dn = dshW[e];
                float m = mcol[e * 68];
                if (dn != cur) {
                    unsafeAtomicAdd(&agg[(unsigned)((cur << 6) + lane)], accum);
                    accum = 0.0f;
                    cur = dn;
                }
                accum += m;
            }
            unsafeAtomicAdd(&agg[(unsigned)((cur << 6) + lane)], accum);
        }
        __builtin_amdgcn_wave_barrier();
    }
}

// Unsorted fallback (round-10 form, known-correct; only if ws too small for sort).
__global__ __launch_bounds__(256) void k_edge_u(
    const int* __restrict__ eidx, const float* __restrict__ eattr,
    const float* __restrict__ dstpack, const float* __restrict__ srcpack,
    const short* __restrict__ wcat_l, float* __restrict__ agg) {
    __shared__ float msgV[2][32][64];
    __shared__ int dsh[32], ssh[32];
    int tid = threadIdx.x;
    int w = tid >> 6;
    int lane = tid & 63;
    int c = lane & 31;
    int h2 = lane >> 5;
    int col = w * 32 + c;
    int dcol = (w & 1) * 32 + c;

    short8v bfr[4];
#pragma unroll
    for (int kk = 0; kk < 4; ++kk) {
#pragma unroll
        for (int e = 0; e < 8; ++e) bfr[kk][e] = wcat_l[(kk * 16 + 8 * h2 + e) * 128 + col];
    }

    for (int tile = blockIdx.x; tile < NTILES; tile += gridDim.x) {
        int e0 = tile * 32;
        if (lane < 32) {
            dsh[lane] = eidx[N_EDGES + e0 + lane];
            ssh[lane] = eidx[e0 + lane];
        }
        short8v afr[4];
        const float* erow = eattr + (size_t)(e0 + c) * EDIM;
#pragma unroll
        for (int kk = 0; kk < 3; ++kk) {
            int k0 = kk * 16 + 8 * h2;
#pragma unroll
            for (int p = 0; p < 4; ++p) {
                float2 v = *(const float2*)(erow + k0 + 2 * p);
                afr[kk][2 * p] = cvt_bf16(v.x);
                afr[kk][2 * p + 1] = cvt_bf16(v.y);
            }
        }
        {
            short8v a;
#pragma unroll
            for (int e = 0; e < 8; ++e) a[e] = 0;
            if (h2 == 0) {
                float2 v = *(const float2*)(erow + 48);
                a[0] = cvt_bf16(v.x);
                a[1] = cvt_bf16(v.y);
            }
            afr[3] = a;
        }
        f32x16 acc;
#pragma unroll
        for (int i = 0; i < 16; ++i) acc[i] = 0.0f;
#pragma unroll
        for (int kk = 0; kk < 4; ++kk)
            acc = __builtin_amdgcn_mfma_f32_32x32x16_bf16(afr[kk], bfr[kk], acc, 0, 0, 0);

        __builtin_amdgcn_wave_barrier();

#pragma unroll
        for (int grp = 0; grp < 2; ++grp) {
            int tI[8], sI[8];
            float dv[8], sv[8];
#pragma unroll
            for (int r = 0; r < 8; ++r) {
                int rr = grp * 8 + r;
                int row = (rr & 3) + 8 * (rr >> 2) + 4 * h2;
                tI[r] = dsh[row];
                sI[r] = ssh[row];
            }
#pragma unroll
            for (int r = 0; r < 8; ++r) {
                dv[r] = dstpack[(unsigned)((tI[r] << 7) + col)];
                sv[r] = srcpack[(unsigned)((sI[r] << 7) + col)];
            }
            float pre[8];
#pragma unroll
            for (int r = 0; r < 8; ++r) pre[r] = acc[grp * 8 + r] + dv[r] + sv[r];
            if (w < 2) {
#pragma unroll
                for (int r = 0; r < 8; ++r) {
                    int rr = grp * 8 + r;
                    int row = (rr & 3) + 8 * (rr >> 2) + 4 * h2;
                    msgV[0][row][dcol] = sigx(pre[r]);
                }
            } else {
#pragma unroll
                for (int r = 0; r < 8; ++r) {
                    int rr = grp * 8 + r;
                    int row = (rr & 3) + 8 * (rr >> 2) + 4 * h2;
                    msgV[1][row][dcol] = spx(pre[r]);
                }
            }
        }
        __syncthreads();
        {
            int d = tid & 63;
            int base = (tid >> 6) * 8;
#pragma unroll
            for (int j = 0; j < 8; ++j) {
                int row = base + j;
                float m = msgV[0][row][d] * msgV[1][row][d];
                unsafeAtomicAdd(&agg[(unsigned)((dsh[row] << 6) + d)], m);
            }
        }
        __syncthreads();
    }
}

// Fused final update + sorted-batch pool: val = softplus(h+agg), run-length
// accumulate, one atomic per graph transition. agg left dirty (re-memset next call).
__global__ __launch_bounds__(256) void k_pool_s(
    const float* __restrict__ h, const float* __restrict__ agg,
    const int* __restrict__ batch,
    float* __restrict__ pooled, float* __restrict__ counts) {
    int tid = threadIdx.x;
    int d = tid & 63;
    int strm = tid >> 6;
    int base = blockIdx.x * 256 + strm * 64;
    if (base >= N_NODES) return;
    int end = min(base + 64, N_NODES);
    float accum = 0.0f;
    int cnt = 0;
    int cur = batch[base];
    for (int n = base; n < end; ++n) {
        int g = batch[n];
        if (g != cur) {
            unsafeAtomicAdd(&pooled[cur * DIM + d], accum);
            if (d == 0) unsafeAtomicAdd(&counts[cur], (float)cnt);
            accum = 0.0f;
            cnt = 0;
            cur = g;
        }
        accum += softplus_f(h[(size_t)n * DIM + d] + agg[(size_t)n * DIM + d]);
        cnt++;
    }
    unsafeAtomicAdd(&pooled[cur * DIM + d], accum);
    if (d == 0) unsafeAtomicAdd(&counts[cur], (float)cnt);
}

__global__ __launch_bounds__(64) void k_mlp(
    const float* __restrict__ pooled, const float* __restrict__ counts,
    const float* __restrict__ W1, const float* __restrict__ b1,
    const float* __restrict__ W2, const float* __restrict__ b2,
    const float* __restrict__ Wo, const float* __restrict__ bo,
    float* __restrict__ out) {
    __shared__ float ps[64];
    __shared__ float h1[128];
    int g = blockIdx.x, lane = threadIdx.x;
    float cnt = fmaxf(counts[g], 1.0f);
    ps[lane] = pooled[g * DIM + lane] / cnt;
    __syncthreads();
#pragma unroll
    for (int rep = 0; rep < 2; ++rep) {
        int j = lane + rep * 64;
        float acc = b1[j];
        for (int k = 0; k < 64; ++k) acc += ps[k] * W1[k * HDIM + j];
        h1[j] = fmaxf(acc, 0.0f);
    }
    __syncthreads();
    float acc = b2[lane];
    for (int k = 0; k < 128; ++k) acc += h1[k] * W2[k * 64 + lane];
    float v = fmaxf(acc, 0.0f) * Wo[lane];
#pragma unroll
    for (int off = 32; off; off >>= 1) v += __shfl_down(v, off);
    if (lane == 0) out[g] = v + bo[0];
}

extern "C" void kernel_launch(void* const* d_in, const int* in_sizes, int n_in,
                              void* d_out, int out_size, void* d_ws, size_t ws_size,
                              hipStream_t stream) {
    const int* x = (const int*)d_in[0];
    const int* eidx = (const int*)d_in[1];
    const float* eattr = (const float*)d_in[2];
    const int* batch = (const int*)d_in[3];
    const float* emb = (const float*)d_in[4];
    const float* Wf = (const float*)d_in[5];
    const float* bf = (const float*)d_in[6];
    const float* Ws = (const float*)d_in[7];
    const float* bs = (const float*)d_in[8];
    const float* W1 = (const float*)d_in[9];
    const float* b1 = (const float*)d_in[10];
    const float* W2 = (const float*)d_in[11];
    const float* b2 = (const float*)d_in[12];
    const float* Wo = (const float*)d_in[13];
    const float* bo = (const float*)d_in[14];
    float* out = (float*)d_out;

    char* p = (char*)d_ws;
    float* h = (float*)p;       p += (size_t)N_NODES * DIM * 4;
    float* dstpack = (float*)p; p += (size_t)N_NODES * 2 * DIM * 4;
    float* srcpack = (float*)p; p += (size_t)N_NODES * 2 * DIM * 4;
    float* agg = (float*)p;     p += (size_t)N_NODES * DIM * 4;
    float* pooled = (float*)p;  p += (size_t)N_GRAPHS * DIM * 4;
    float* counts = (float*)p;  p += (size_t)N_GRAPHS * 4;
    short* wcat = (short*)p;    p += (size_t)NLAYER * 64 * 128 * 2;
    short* eattrP = (short*)p;  p += (size_t)NTILES * 4 * 64 * 8 * 2;  // 102.4 MB
    int* hist = (int*)p;        p += (size_t)N_NODES * 4;
    int* scanbuf = (int*)p;     p += (size_t)N_NODES * 4;
    int* blocksums = (int*)p;   p += 256 * 4;
    int* cursor = (int*)p;      p += (size_t)N_NODES * 4;
    int* perm = (int*)p;        p += (size_t)N_EDGES * 4;
    int* permSrc = (int*)p;     p += (size_t)N_EDGES * 4;
    int* permDst = (int*)p;     p += (size_t)N_EDGES * 4;
    size_t used_sorted = (size_t)(p - (char*)d_ws);

    bool sorted = used_sorted <= ws_size;

    const int SCAN_BLOCKS = (N_NODES + 255) / 256;  // 196
    const int NODEMM_BLOCKS = (N_NODES + 63) / 64;  // 782

    k_wcat<<<NLAYER * 64 * 128 / 256, 256, 0, stream>>>(Wf, Ws, wcat);
    if (sorted) {
        hipMemsetAsync(hist, 0, (size_t)N_NODES * 4, stream);
        k_hist<<<N_EDGES / 256, 256, 0, stream>>>(eidx, hist);
        k_scan1<<<SCAN_BLOCKS, 256, 0, stream>>>(hist, scanbuf, blocksums);
        k_scan2<<<1, 256, 0, stream>>>(blocksums, SCAN_BLOCKS);
        k_scan3<<<SCAN_BLOCKS, 256, 0, stream>>>(scanbuf, hist, blocksums, cursor);
        k_scatter<<<N_EDGES / 256, 256, 0, stream>>>(eidx, cursor, perm, permSrc, permDst);
        k_eprep2<<<NTILES * 64 / 256, 256, 0, stream>>>(eattr, perm, eattrP);
    }
    hipMemsetAsync(agg, 0, (size_t)N_NODES * DIM * 4, stream);
    for (int l = 0; l < NLAYER; ++l) {
        const float* Wfl = Wf + (size_t)l * ZDIM * DIM;
        const float* Wsl = Ws + (size_t)l * ZDIM * DIM;
        if (l == 0) {
            k_nodemm<2><<<NODEMM_BLOCKS, 256, 0, stream>>>(
                nullptr, h, nullptr, x, emb, Wfl, bf + l * DIM, Wsl, bs + l * DIM,
                dstpack, srcpack);
        } else {
            k_nodemm<1><<<NODEMM_BLOCKS, 256, 0, stream>>>(
                h, h, agg, nullptr, nullptr, Wfl, bf + l * DIM, Wsl, bs + l * DIM,
                dstpack, srcpack);
        }
        if (sorted) {
            k_edge_s<<<2048, 256, 0, stream>>>(permSrc, permDst, eattrP, dstpack, srcpack,
                                               wcat + (size_t)l * 64 * 128, agg);
        } else {
            k_edge_u<<<2048, 256, 0, stream>>>(eidx, eattr, dstpack, srcpack,
                                               wcat + (size_t)l * 64 * 128, agg);
        }
    }
    hipMemsetAsync(pooled, 0, ((size_t)N_GRAPHS * DIM + N_GRAPHS) * 4, stream);
    k_pool_s<<<(N_NODES + 255) / 256, 256, 0, stream>>>(h, agg, batch, pooled, counts);
    k_mlp<<<N_GRAPHS, 64, 0, stream>>>(pooled, counts, W1, b1, W2, b2, Wo, bo, out);
}